// Round 4
// baseline (81.728 us; speedup 1.0000x reference)
//
#include <hip/hip_runtime.h>

// Problem constants (fixed by the reference)
#define BB 2048
#define CC 50
#define DD 512
#define HH 51   // D // 10

// async global->LDS, 16B per lane: writes ldsbase + lane*16
#define GLDS16(gsrc, ldst) \
    __builtin_amdgcn_global_load_lds( \
        (const __attribute__((address_space(1))) void*)(gsrc), \
        (__attribute__((address_space(3))) void*)(ldst), 16, 0, 0)

__global__ __launch_bounds__(512, 4) void ConstraintFuser_kernel(
    const float* __restrict__ q,      // [B, D]
    const int*   __restrict__ heads,  // [B, C]
    const int*   __restrict__ tails,  // [B, C]
    const int*   __restrict__ rels,   // [B, C]
    const float* __restrict__ ent,    // [NE+1, D]
    const float* __restrict__ rel,    // [NR+1, D]
    const float* __restrict__ w1,     // [D, H]
    const float* __restrict__ b1,     // [H]
    const float* __restrict__ w2,     // [H, D]
    const float* __restrict__ b2,     // [D]
    float* __restrict__ out)          // [B, D]
{
    const int b    = blockIdx.x;
    const int tid  = threadIdx.x;
    const int wave = tid >> 6;
    const int lane = tid & 63;

    // 32 KB: per-wave double-buffered t-row DMA slots.
    // Reused after the gather loop: s_tslot[w][0] = wave-w pooled partial (2 KB),
    // then rows 0..3 (cast) as the 4x128 float4 epilogue reduce buffer.
    __shared__ float4 s_tslot[8][2][128];
    __shared__ float  s_q[DD];          // 2 KB
    __shared__ float  s_pool[DD];       // 2 KB
    __shared__ float  s_wred[8][HH];
    __shared__ float  s_mid[HH];
    __shared__ int    s_h[CC], s_t[CC], s_r[CC];

    // ---- stage indices + query row ----
    if (tid < CC) {
        s_h[tid] = heads[b * CC + tid];
        s_t[tid] = tails[b * CC + tid];
        s_r[tid] = rels [b * CC + tid];
    }
    if (tid < 128) {
        ((float4*)s_q)[tid] = ((const float4*)(q + (size_t)b * DD))[tid];
    }
    __syncthreads();

    // lane's elements: float4 #lane and #(lane+64)  (8-way bank floor on b128)
    const float4 q0 = ((const float4*)s_q)[lane];
    const float4 q1 = ((const float4*)s_q)[lane + 64];

    const int Ni = (CC - wave + 7) >> 3;   // 7 for waves 0-1, 6 for waves 2-7

    // ---- prologue: issue c0 = wave and c1 = wave+8 (6 vm ops each) ----
    {
        const float4* trow = (const float4*)(ent + (size_t)s_t[wave] * DD);
        GLDS16(trow + lane,      &s_tslot[wave][0][0]);
        GLDS16(trow + 64 + lane, &s_tslot[wave][0][64]);
    }
    const float4* hrow = (const float4*)(ent + (size_t)s_h[wave] * DD);
    const float4* rrow = (const float4*)(rel + (size_t)s_r[wave] * DD);
    float4 h0 = hrow[lane], h1 = hrow[lane + 64];
    float4 r0 = rrow[lane], r1 = rrow[lane + 64];
    {
        const int c1 = wave + 8;
        const float4* trowN = (const float4*)(ent + (size_t)s_t[c1] * DD);
        GLDS16(trowN + lane,      &s_tslot[wave][1][0]);
        GLDS16(trowN + 64 + lane, &s_tslot[wave][1][64]);
    }
    const float4* hrowN = (const float4*)(ent + (size_t)s_h[wave + 8] * DD);
    const float4* rrowN = (const float4*)(rel + (size_t)s_r[wave + 8] * DD);
    float4 h0n = hrowN[lane], h1n = hrowN[lane + 64];
    float4 r0n = rrowN[lane], r1n = rrowN[lane + 64];

    float4 acc0 = make_float4(0.f, 0.f, 0.f, 0.f);
    float4 acc1 = make_float4(0.f, 0.f, 0.f, 0.f);

    // ---- barrier-free per-wave gather pipeline, issue-ahead-by-2 ----
    for (int i = 0; i < Ni; ++i) {
        // c_i's 6 ops are older than c_{i+1}'s 6 outstanding -> vmcnt(6).
        if (i + 1 < Ni) {
            asm volatile("s_waitcnt vmcnt(6)" ::: "memory");
        } else {
            asm volatile("s_waitcnt vmcnt(0)" ::: "memory");
        }

        // score for c_i (h regs prefetched 2 iters ago)
        float p = q0.x * h0.x + q0.y * h0.y + q0.z * h0.z + q0.w * h0.w
                + q1.x * h1.x + q1.y * h1.y + q1.z * h1.z + q1.w * h1.w;
        #pragma unroll
        for (int off = 32; off > 0; off >>= 1) p += __shfl_xor(p, off, 64);

        // consume staged t row from this wave's private slot
        const float4 t0 = s_tslot[wave][i & 1][lane];
        const float4 t1 = s_tslot[wave][i & 1][lane + 64];
        acc0.x += p * (t0.x + r0.x);
        acc0.y += p * (t0.y + r0.y);
        acc0.z += p * (t0.z + r0.z);
        acc0.w += p * (t0.w + r0.w);
        acc1.x += p * (t1.x + r1.x);
        acc1.y += p * (t1.y + r1.y);
        acc1.z += p * (t1.z + r1.z);
        acc1.w += p * (t1.w + r1.w);

        // rotate register prefetch: cur <- next
        h0 = h0n; h1 = h1n; r0 = r0n; r1 = r1n;

        // fence: LDS reads of slot[i&1] complete before DMA re-targets it
        asm volatile("s_waitcnt lgkmcnt(0)" ::: "memory");

        // issue c_{i+2} into the just-freed slot
        const int cn = wave + 8 * (i + 2);
        if (cn < CC) {
            const float4* trow2 = (const float4*)(ent + (size_t)s_t[cn] * DD);
            float4* slot2 = &s_tslot[wave][i & 1][0];
            GLDS16(trow2 + lane,      slot2);
            GLDS16(trow2 + 64 + lane, slot2 + 64);
            const float4* hrow2 = (const float4*)(ent + (size_t)s_h[cn] * DD);
            const float4* rrow2 = (const float4*)(rel + (size_t)s_r[cn] * DD);
            h0n = hrow2[lane]; h1n = hrow2[lane + 64];
            r0n = rrow2[lane]; r1n = rrow2[lane + 64];
        }
    }

    // ---- per-wave pooled partial into union'd region (all vm drained above) ----
    {
        float4* pp_w = &s_tslot[wave][0][0];
        pp_w[lane]      = acc0;
        pp_w[lane + 64] = acc1;
    }
    __syncthreads();

    // ---- reduce 8 per-wave partials -> s_pool ----
    if (tid < 128) {
        float4 s = s_tslot[0][0][tid];
        #pragma unroll
        for (int w = 1; w < 8; ++w) {
            const float4 a = s_tslot[w][0][tid];
            s.x += a.x; s.y += a.y; s.z += a.z; s.w += a.w;
        }
        ((float4*)s_pool)[tid] = s;
    }
    __syncthreads();

    // ---- phase 3: mid = relu(pooled @ w1 + b1); wave w owns d in [64w, 64w+64) ----
    if (lane < HH) {
        const int d0 = wave * 64;
        float partial = 0.f;
        #pragma unroll 8
        for (int j = 0; j < 64; ++j) {
            partial += s_pool[d0 + j] * w1[(size_t)(d0 + j) * HH + lane];
        }
        s_wred[wave][lane] = partial;
    }
    __syncthreads();
    if (tid < HH) {
        float m = b1[tid];
        #pragma unroll
        for (int w = 0; w < 8; ++w) m += s_wred[w][tid];
        s_mid[tid] = m > 0.f ? m : 0.f;
    }
    __syncthreads();

    // ---- phase 4: out = mid @ w2 + b2 + q ----
    const int cg = tid >> 7;    // 0..3
    const int dv = tid & 127;   // float4 index within row
    float4 acc2 = make_float4(0.f, 0.f, 0.f, 0.f);
    #pragma unroll
    for (int i = 0; i < 13; ++i) {
        const int h = cg + i * 4;
        if (h < HH) {
            const float  m  = s_mid[h];
            const float4 wv = ((const float4*)(w2 + (size_t)h * DD))[dv];
            acc2.x += m * wv.x;
            acc2.y += m * wv.y;
            acc2.z += m * wv.z;
            acc2.w += m * wv.w;
        }
    }
    float4 (*s_red4)[128] = (float4 (*)[128])&s_tslot[0][0][0];   // reuse dead LDS
    s_red4[cg][dv] = acc2;
    __syncthreads();
    if (tid < 128) {
        const float4 a0 = s_red4[0][tid];
        const float4 a1 = s_red4[1][tid];
        const float4 a2 = s_red4[2][tid];
        const float4 a3 = s_red4[3][tid];
        const float4 bb = ((const float4*)b2)[tid];
        const float4 qq = ((const float4*)s_q)[tid];
        float4 o;
        o.x = a0.x + a1.x + a2.x + a3.x + bb.x + qq.x;
        o.y = a0.y + a1.y + a2.y + a3.y + bb.y + qq.y;
        o.z = a0.z + a1.z + a2.z + a3.z + bb.z + qq.z;
        o.w = a0.w + a1.w + a2.w + a3.w + bb.w + qq.w;
        ((float4*)(out + (size_t)b * DD))[tid] = o;
    }
}

extern "C" void kernel_launch(void* const* d_in, const int* in_sizes, int n_in,
                              void* d_out, int out_size, void* d_ws, size_t ws_size,
                              hipStream_t stream) {
    const float* q     = (const float*)d_in[0];
    const int*   heads = (const int*)  d_in[1];
    const int*   tails = (const int*)  d_in[2];
    const int*   rels  = (const int*)  d_in[3];
    const float* ent   = (const float*)d_in[4];
    const float* rel   = (const float*)d_in[5];
    const float* w1    = (const float*)d_in[6];
    const float* b1    = (const float*)d_in[7];
    const float* w2    = (const float*)d_in[8];
    const float* b2    = (const float*)d_in[9];
    float* out = (float*)d_out;

    ConstraintFuser_kernel<<<BB, 512, 0, stream>>>(
        q, heads, tails, rels, ent, rel, w1, b1, w2, b2, out);
}